// Round 3
// baseline (1953.509 us; speedup 1.0000x reference)
//
#include <hip/hip_runtime.h>
#include <math.h>

#define N_PTS 32768
#define DIM   512
#define K_CL  64
#define ITERS 10
#define EPS_F 1e-8f

// ws layout (floats):
//   ct:     [0, 32768)       transposed centers ct[d*64 + k]
//   sums:   [32768, 65536)   sums[k*512 + d]
//   c2:     [65536, 65600)
//   counts: int32 at float offset 65600
// d_out doubles as per-cluster index lists during iterations.

__global__ void init_centers(const float* __restrict__ x,
                             float* __restrict__ ct,
                             float* __restrict__ c2) {
    int k = blockIdx.x;
    int t = threadIdx.x;
    float ssum = 0.f;
    for (int d = t; d < DIM; d += 256) {
        float v = x[k * DIM + d];
        ct[d * K_CL + k] = v;
        ssum += v * v;
    }
    #pragma unroll
    for (int off = 32; off; off >>= 1) ssum += __shfl_down(ssum, off);
    __shared__ float red[4];
    if ((t & 63) == 0) red[t >> 6] = ssum;
    __syncthreads();
    if (t == 0) c2[k] = red[0] + red[1] + red[2] + red[3];
}

// ---- shared staging/prefetch machinery (assign + final) --------------------
// centers tile (32 dims x 64 cl = 8 KB) DMA'd to LDS one t-iter ahead;
// x prefetched distance-2 through 4 register slots (slot = kkq & 3).

#define DMA_CS(tt, bb)                                                         \
    {                                                                          \
        _Pragma("unroll")                                                      \
        for (int q_ = 0; q_ < 4; ++q_) {                                       \
            __builtin_amdgcn_global_load_lds(                                  \
                (const __attribute__((address_space(1))) void*)                \
                    (ct + (tt) * 2048 + q_ * 512 + tid * 4),                   \
                (__attribute__((address_space(3))) void*)                      \
                    (&cs[bb][q_ * 512 + tid * 4]),                             \
                16, 0, 0);                                                     \
        }                                                                      \
    }

#define XPREF(slot, kkflat)                                                    \
    {                                                                          \
        const int kw_ = (kkflat) & 127;                                        \
        _Pragma("unroll")                                                      \
        for (int i_ = 0; i_ < 8; ++i_)                                         \
            X[slot][i_] = *(const float4*)(xb + (size_t)i_ * DIM + kw_ * 4);   \
    }

#define CVLOAD(slot, kq)                                                       \
    {                                                                          \
        const float* cb_ = &cs[buf][(kq) * 256 + c * 4];                       \
        cv[slot][0] = *(const float4*)(cb_);                                   \
        cv[slot][1] = *(const float4*)(cb_ + 64);                              \
        cv[slot][2] = *(const float4*)(cb_ + 128);                             \
        cv[slot][3] = *(const float4*)(cb_ + 192);                             \
    }

// dims strictly ascending per acc[i][j]: bitwise-identical dots to round 1/2
#define BODY_DOT(kq)                                                           \
    {                                                                          \
        if ((kq) < 7) { CVLOAD((kq + 1) & 1, (kq) + 1); }                      \
        XPREF(((kq) + 2) & 3, t * 8 + (kq) + 2);                               \
        const float4 c0 = cv[(kq) & 1][0], c1 = cv[(kq) & 1][1];               \
        const float4 c2v = cv[(kq) & 1][2], c3 = cv[(kq) & 1][3];              \
        _Pragma("unroll")                                                      \
        for (int i = 0; i < 8; ++i) {                                          \
            const float4 xq = X[(kq) & 3][i];                                  \
            acc[i][0] += xq.x * c0.x;  acc[i][1] += xq.x * c0.y;               \
            acc[i][2] += xq.x * c0.z;  acc[i][3] += xq.x * c0.w;               \
            acc[i][0] += xq.y * c1.x;  acc[i][1] += xq.y * c1.y;               \
            acc[i][2] += xq.y * c1.z;  acc[i][3] += xq.y * c1.w;               \
            acc[i][0] += xq.z * c2v.x; acc[i][1] += xq.z * c2v.y;              \
            acc[i][2] += xq.z * c2v.z; acc[i][3] += xq.z * c2v.w;              \
            acc[i][0] += xq.w * c3.x;  acc[i][1] += xq.w * c3.y;               \
            acc[i][2] += xq.w * c3.z;  acc[i][3] += xq.w * c3.w;               \
        }                                                                      \
    }

#define BODY_DIST(kq)                                                          \
    {                                                                          \
        if ((kq) < 7) { CVLOAD((kq + 1) & 1, (kq) + 1); }                      \
        XPREF(((kq) + 2) & 3, t * 8 + (kq) + 2);                               \
        const float4 c0 = cv[(kq) & 1][0], c1 = cv[(kq) & 1][1];               \
        const float4 c2v = cv[(kq) & 1][2], c3 = cv[(kq) & 1][3];              \
        _Pragma("unroll")                                                      \
        for (int i = 0; i < 8; ++i) {                                          \
            const float4 xq = X[(kq) & 3][i];                                  \
            float d0, d1, d2, d3;                                              \
            d0 = xq.x - c0.x; acc[i][0] += d0 * d0;                            \
            d1 = xq.x - c0.y; acc[i][1] += d1 * d1;                            \
            d2 = xq.x - c0.z; acc[i][2] += d2 * d2;                            \
            d3 = xq.x - c0.w; acc[i][3] += d3 * d3;                            \
            d0 = xq.y - c1.x; acc[i][0] += d0 * d0;                            \
            d1 = xq.y - c1.y; acc[i][1] += d1 * d1;                            \
            d2 = xq.y - c1.z; acc[i][2] += d2 * d2;                            \
            d3 = xq.y - c1.w; acc[i][3] += d3 * d3;                            \
            d0 = xq.z - c2v.x; acc[i][0] += d0 * d0;                           \
            d1 = xq.z - c2v.y; acc[i][1] += d1 * d1;                           \
            d2 = xq.z - c2v.z; acc[i][2] += d2 * d2;                           \
            d3 = xq.z - c2v.w; acc[i][3] += d3 * d3;                           \
            d0 = xq.w - c3.x; acc[i][0] += d0 * d0;                            \
            d1 = xq.w - c3.y; acc[i][1] += d1 * d1;                            \
            d2 = xq.w - c3.z; acc[i][2] += d2 * d2;                            \
            d3 = xq.w - c3.w; acc[i][3] += d3 * d3;                            \
        }                                                                      \
    }

// 64 points x 64 clusters per 128-thread block; 8 pts x 4 cl per thread.
__launch_bounds__(128)
__global__ void assign_scatter(const float* __restrict__ x,
                               const float* __restrict__ ct,
                               const float* __restrict__ c2,
                               int* __restrict__ counts,
                               int* __restrict__ lists) {
    __shared__ float cs[2][2048];
    __shared__ float c2s[K_CL];

    const int tid = threadIdx.x;
    const int pbase = blockIdx.x * 64;
    const int rr = tid >> 4;   // 0..7 point group (8 pts each)
    const int c  = tid & 15;   // cluster quad
    if (tid < K_CL) c2s[tid] = c2[tid];

    const float* xb = x + (size_t)(pbase + rr * 8) * DIM;

    float4 X[4][8];
    float4 cv[2][4];
    float acc[8][4] = {};

    DMA_CS(0, 0);
    XPREF(0, 0);
    XPREF(1, 1);
    __syncthreads();   // drains DMA(0) + X(0),X(1)

    int buf = 0;
    for (int t = 0; t < 16; ++t) {
        if (t < 15) DMA_CS(t + 1, buf ^ 1);
        CVLOAD(0, 0);
        BODY_DOT(0); BODY_DOT(1); BODY_DOT(2); BODY_DOT(3);
        BODY_DOT(4); BODY_DOT(5); BODY_DOT(6); BODY_DOT(7);
        __syncthreads();
        buf ^= 1;
    }

    #pragma unroll
    for (int i = 0; i < 8; ++i) {
        float bv = 1e30f; int bc = 0;
        #pragma unroll
        for (int j = 0; j < 4; ++j) {
            float v = c2s[c * 4 + j] - 2.0f * acc[i][j];
            if (v < bv) { bv = v; bc = c * 4 + j; }
        }
        #pragma unroll
        for (int m = 1; m < 16; m <<= 1) {
            float ov = __shfl_xor(bv, m);
            int   oc = __shfl_xor(bc, m);
            if (ov < bv || (ov == bv && oc < bc)) { bv = ov; bc = oc; }
        }
        if (c == 0) {
            int p = pbase + rr * 8 + i;
            int slot = atomicAdd(&counts[bc], 1);
            lists[bc * N_PTS + slot] = p;
        }
    }
}

__global__ void gather_sums(const float* __restrict__ x,
                            const int* __restrict__ lists,
                            const int* __restrict__ counts,
                            float* __restrict__ sums) {
    int k  = blockIdx.x;
    int dc = blockIdx.y;
    int pc = blockIdx.z;
    int t  = threadIdx.x;
    int n  = counts[k];
    int s0 = (n * pc) >> 3;
    int s1 = (n * (pc + 1)) >> 3;
    int d  = dc * 128 + t;
    const int* lst = lists + k * N_PTS;
    float acc = 0.f;
    int s = s0;
    for (; s + 8 <= s1; s += 8) {
        int idx[8];
        #pragma unroll
        for (int q = 0; q < 8; ++q) idx[q] = lst[s + q];
        #pragma unroll
        for (int q = 0; q < 8; ++q) acc += x[(size_t)idx[q] * DIM + d];
    }
    for (; s < s1; ++s) acc += x[(size_t)lst[s] * DIM + d];
    atomicAdd(&sums[k * DIM + d], acc);
}

__global__ void update_centers(float* __restrict__ ct,
                               const float* __restrict__ sums,
                               const int* __restrict__ counts,
                               float* __restrict__ c2) {
    int k = blockIdx.x;
    int t = threadIdx.x;
    int cnt = counts[k];
    float fc = (float)cnt;
    float ssum = 0.f;
    for (int d = t; d < DIM; d += 256) {
        float v = ct[d * K_CL + k];
        if (cnt > 0) v = sums[k * DIM + d] / fc;
        ct[d * K_CL + k] = v;
        ssum += v * v;
    }
    #pragma unroll
    for (int off = 32; off; off >>= 1) ssum += __shfl_down(ssum, off);
    __shared__ float red[4];
    if ((t & 63) == 0) red[t >> 6] = ssum;
    __syncthreads();
    if (t == 0) c2[k] = red[0] + red[1] + red[2] + red[3];
}

// Final distances via direct differencing (exact 0 at singletons).
__launch_bounds__(128)
__global__ void final_dist(const float* __restrict__ x,
                           const float* __restrict__ ct,
                           float* __restrict__ out) {
    __shared__ float cs[2][2048];

    const int tid = threadIdx.x;
    const int pbase = blockIdx.x * 64;
    const int rr = tid >> 4;
    const int c  = tid & 15;

    const float* xb = x + (size_t)(pbase + rr * 8) * DIM;

    float4 X[4][8];
    float4 cv[2][4];
    float acc[8][4] = {};

    DMA_CS(0, 0);
    XPREF(0, 0);
    XPREF(1, 1);
    __syncthreads();

    int buf = 0;
    for (int t = 0; t < 16; ++t) {
        if (t < 15) DMA_CS(t + 1, buf ^ 1);
        CVLOAD(0, 0);
        BODY_DIST(0); BODY_DIST(1); BODY_DIST(2); BODY_DIST(3);
        BODY_DIST(4); BODY_DIST(5); BODY_DIST(6); BODY_DIST(7);
        __syncthreads();
        buf ^= 1;
    }

    #pragma unroll
    for (int i = 0; i < 8; ++i) {
        int p = pbase + rr * 8 + i;
        float4 o;
        o.x = 1.0f / (sqrtf(acc[i][0]) + EPS_F);
        o.y = 1.0f / (sqrtf(acc[i][1]) + EPS_F);
        o.z = 1.0f / (sqrtf(acc[i][2]) + EPS_F);
        o.w = 1.0f / (sqrtf(acc[i][3]) + EPS_F);
        *(float4*)(out + (size_t)p * K_CL + c * 4) = o;
    }
}

extern "C" void kernel_launch(void* const* d_in, const int* in_sizes, int n_in,
                              void* d_out, int out_size, void* d_ws, size_t ws_size,
                              hipStream_t stream) {
    (void)in_sizes; (void)n_in; (void)out_size; (void)ws_size;
    const float* x = (const float*)d_in[0];
    float* ws      = (float*)d_ws;
    float* ct      = ws;
    float* sums    = ws + 32768;
    float* c2      = ws + 65536;
    int*   counts  = (int*)(ws + 65600);
    int*   lists   = (int*)d_out;
    float* out     = (float*)d_out;

    init_centers<<<64, 256, 0, stream>>>(x, ct, c2);
    for (int it = 0; it < ITERS; ++it) {
        hipMemsetAsync(counts, 0, K_CL * sizeof(int), stream);
        hipMemsetAsync(sums, 0, K_CL * DIM * sizeof(float), stream);
        assign_scatter<<<512, 128, 0, stream>>>(x, ct, c2, counts, lists);
        gather_sums<<<dim3(64, 4, 8), 128, 0, stream>>>(x, lists, counts, sums);
        update_centers<<<64, 256, 0, stream>>>(ct, sums, counts, c2);
    }
    final_dist<<<512, 128, 0, stream>>>(x, ct, out);
}